// Round 10
// baseline (3257.877 us; speedup 1.0000x reference)
//
#include <hip/hip_runtime.h>
#include <hip/hip_bf16.h>

// Gated Transformer-XL forward.
// Dims: L=4, D=1024, NH=16, HD=64, CUR=512, MEM=512, BS=8, IN=512, FF=4096, FULL=1024
// Activation layout: (seq*BS, D), row = i*BS + b. All activations bf16.

typedef __attribute__((ext_vector_type(8))) __bf16 bfrag;
typedef __attribute__((ext_vector_type(4))) float f4;
typedef __attribute__((ext_vector_type(4))) unsigned short u16x4;
typedef __attribute__((ext_vector_type(8))) unsigned short u16x8;

__device__ __forceinline__ unsigned short f2bf(float f){
  union { float f; unsigned u; } v; v.f = f;
  unsigned r = v.u + 0x7fffu + ((v.u >> 16) & 1u);
  return (unsigned short)(r >> 16);
}
__device__ __forceinline__ float bf2f(unsigned short u){
  union { unsigned u; float f; } v; v.u = (unsigned)u << 16; return v.f;
}
__device__ __forceinline__ float geluf(float x){
  return 0.5f * x * (1.0f + erff(x * 0.7071067811865476f));
}
__device__ __forceinline__ float sigm(float x){ return 1.0f/(1.0f + __expf(-x)); }

__device__ __forceinline__ void gl_lds(const void* g, void* l){
  __builtin_amdgcn_global_load_lds(
    reinterpret_cast<const __attribute__((address_space(1))) unsigned int*>(
        reinterpret_cast<unsigned long>(g)),
    reinterpret_cast<__attribute__((address_space(3))) unsigned int*>(
        reinterpret_cast<unsigned long>(l)),
    16, 0, 0);
}

// ---------------------------------------------------------------------------
// Dense GEMM: C[M,N] = A[M,K] @ B[N,K]^T (bf16, row-major). Optional K-concat.
// BK=64 mega-steps (4 LDS buffers, one barrier per 64-K). XCD-aware swizzle.
// EPI: 6  O1 = bf(gelu(acc + bias1))
//      11 z==0: O1 = bf(sigm(acc) * XB)  (GRU r-gate * x) | z==1: O2 = bf(sigm(acc-2))
//      12 o = (1-Z)*X + Z*tanh(acc); O1 = bf(o)            (GRU combine)
//      14 as 12 but OF[d_out] = o, f32, (b,i)-transposed   (final layer)
//      13 fused QKV+R: z=0 kh, z=1 vhT-scatter, z=2 qU/qV(+bias, *0.125), z=3 rh
// ---------------------------------------------------------------------------
struct GP {
  const unsigned short* A;
  const unsigned short* A2;
  const unsigned short* B;
  const unsigned short* B2;
  unsigned short* O1;
  unsigned short* O2;
  unsigned short* O3;
  unsigned short* O4;
  unsigned short* O5;
  float* OF;
  const float* bias1;
  const float* bias2;
  const unsigned short* XB;
  const unsigned short* ZB;
  int K, Ksplit, lda, ldb, ldo;
  int sBz;
};

template<int BM, int BN, int EPI>
__global__ __launch_bounds__(256) void gemm_k(GP p){
  __shared__ unsigned short As[2][2][BM*32];
  __shared__ unsigned short Bs[2][2][BN*32];
  const int tid  = threadIdx.x;
  const int lane = tid & 63;
  const int wid  = tid >> 6;
  const int lr   = lane & 15;
  const int lg   = lane >> 4;
  constexpr int FM = BM/32, FN = BN/32;

  // XCD swizzle (bijective; all grids have nwg%8==0)
  int bx = blockIdx.x, by = blockIdx.y;
  {
    const int gx = gridDim.x;
    const int nwg = gx * gridDim.y;
    if ((nwg & 7) == 0){
      const int bid = by*gx + bx;
      const int vid = (bid & 7)*(nwg >> 3) + (bid >> 3);
      bx = vid % gx;
      by = vid / gx;
    }
  }
  const int m0 = by * BM;
  const int n0 = bx * BN;
  const int z  = blockIdx.z;

  const unsigned short* Abase = p.A;
  const unsigned short* Bbase = p.B;
  if constexpr (EPI==13){
    if (z==2){ if (by >= 32) return; Abase = p.A + 4194304; }
    if (z==3){ if (by >= 8)  return; Abase = p.A2; }
    const int zsel = (z==0)?1:((z==1)?2:((z==2)?0:3));
    Bbase = p.B + (long)zsel*1048576;
  }

  const int ksp = p.Ksplit ? p.Ksplit : p.K;
  const unsigned short* AbL = Abase + (long)m0*p.lda;
  const unsigned short* AbH = p.A2 && EPI!=13 ? (p.A2 + (long)m0*p.lda - ksp) : AbL;
  const unsigned short* BbL = Bbase + (long)z*p.sBz + (long)n0*p.ldb;
  const unsigned short* BbH = p.B2 ? (p.B2 + (long)z*p.sBz + (long)n0*p.ldb - ksp) : BbL;

  const int srow = tid >> 2;          // 0..63
  const int skk  = (tid & 3) * 8;

  f4 acc[FM][FN];
  f4 zero4 = {0.0f, 0.0f, 0.0f, 0.0f};
  #pragma unroll
  for (int m=0;m<FM;m++)
    #pragma unroll
    for (int n=0;n<FN;n++) acc[m][n] = zero4;

  auto stage = [&](int buf, int sub, int k0){
    const unsigned short* A_ = (k0 < ksp) ? AbL : AbH;
    #pragma unroll
    for (int q=0;q<BM/64;q++)
      gl_lds(A_ + (long)(q*64 + srow)*p.lda + k0 + skk, (char*)As[buf][sub] + q*4096 + wid*1024);
    const unsigned short* B_ = (k0 < ksp) ? BbL : BbH;
    #pragma unroll
    for (int q=0;q<BN/64;q++)
      gl_lds(B_ + (long)(q*64 + srow)*p.ldb + k0 + skk, (char*)Bs[buf][sub] + q*4096 + wid*1024);
  };

  const int nk2 = p.K >> 6;
  stage(0,0,0); stage(0,1,32);
  __syncthreads();

  int cur = 0;
  for (int t = 0; t < nk2; ++t){
    if (t+1 < nk2){
      stage(cur^1, 0, (t+1)*64);
      stage(cur^1, 1, (t+1)*64 + 32);
    }
    #pragma unroll
    for (int sub=0; sub<2; ++sub){
      bfrag af[FM], bfr[FN];
      #pragma unroll
      for (int m=0;m<FM;m++)
        af[m] = *(const bfrag*)&As[cur][sub][((wid>>1)*(BM/2) + m*16 + lr)*32 + lg*8];
      #pragma unroll
      for (int n=0;n<FN;n++)
        bfr[n] = *(const bfrag*)&Bs[cur][sub][((wid&1)*(BN/2) + n*16 + lr)*32 + lg*8];
      #pragma unroll
      for (int m=0;m<FM;m++)
        #pragma unroll
        for (int n=0;n<FN;n++)
          acc[m][n] = __builtin_amdgcn_mfma_f32_16x16x32_bf16(af[m], bfr[n], acc[m][n], 0, 0, 0);
    }
    __syncthreads();   // drains vmcnt(0): mega-tile t+1 resident; buffers reusable
    cur ^= 1;
  }

  const int wr0 = m0 + (wid>>1)*(BM/2);
  const int wc0 = n0 + (wid&1)*(BN/2);
  #pragma unroll
  for (int m=0;m<FM;m++)
    #pragma unroll
    for (int n=0;n<FN;n++)
      #pragma unroll
      for (int r=0;r<4;r++){
        const int gr = wr0 + m*16 + lg*4 + r;
        const int gc = wc0 + n*16 + lr;
        const float a = acc[m][n][r];
        const long base = (long)gr*p.ldo + gc;
        if constexpr (EPI==6){
          const float t = a + (p.bias1 ? p.bias1[gc] : 0.0f);
          p.O1[base] = f2bf(geluf(t));
        }
        else if constexpr (EPI==11){
          const long ix = (long)gr*1024 + gc;
          if (z==0) p.O1[ix] = f2bf(sigm(a) * bf2f(p.XB[ix]));
          else      p.O2[ix] = f2bf(sigm(a - 2.0f));
        }
        else if constexpr (EPI==12){
          const long ix = (long)gr*1024 + gc;
          const float zz = bf2f(p.ZB[ix]);
          const float oo = (1.0f - zz)*bf2f(p.XB[ix]) + zz*tanhf(a);
          p.O1[ix] = f2bf(oo);
        }
        else if constexpr (EPI==14){
          const long ix = (long)gr*1024 + gc;
          const float zz = bf2f(p.ZB[ix]);
          const float oo = (1.0f - zz)*bf2f(p.XB[ix]) + zz*tanhf(a);
          const int i_ = gr >> 3, b_ = gr & 7;
          p.OF[(long)b_*524288 + (long)i_*1024 + gc] = oo;
        }
        else if constexpr (EPI==13){
          const long ix = (long)gr*1024 + gc;
          if (z==0){ p.O1[ix] = f2bf(a); }
          else if (z==1){
            const int b_ = gr & 7, js = gr >> 3, h_ = gc >> 6, d_ = gc & 63;
            p.O2[(long)(b_*16 + h_)*65536 + (long)d_*1024 + js] = f2bf(a);
          }
          else if (z==2){ p.O3[ix] = f2bf((a + p.bias1[gc])*0.125f);
                          p.O4[ix] = f2bf((a + p.bias2[gc])*0.125f); }
          else { p.O5[ix] = f2bf(a); }
        }
      }
}

// ---------------------------------------------------------------------------
// Fused relative attention (round-8 body, occupancy raised to 5 waves/EU:
// VGPR_Count=84 <= 102 budget, LDS 21.5KB allows 7 blocks/CU — prior (256,3)
// cap was the latency-hiding limiter).
// ---------------------------------------------------------------------------
__global__ __launch_bounds__(256,5) void attn_k(const unsigned short* __restrict__ qU,
                                                const unsigned short* __restrict__ qV,
                                                const unsigned short* __restrict__ kh,
                                                const unsigned short* __restrict__ rh,
                                                const unsigned short* __restrict__ vhT,
                                                unsigned short* __restrict__ ctx){
  __shared__ char Sm[20480];          // band (528*38=20064) / P-chunks (4KB) / po @4096 (16KB)
  __shared__ float redm[4][16];
  __shared__ float reds[4][16];
  __shared__ float invd[16];
  const int tid = threadIdx.x;
  const int w   = tid >> 6;
  const int lane= tid & 63;
  const int lr  = lane & 15;
  const int lg  = lane >> 4;
  const int id = blockIdx.x;
  const int b  = id & 7;              // id%8 -> XCD: per-b kh/vhT slice stays in one L2
  const int i0 = ((id >> 3) & 31) * 16;
  const int h  = id >> 8;
  const int gmax = i0 >> 4;           // last valid 16-col group in half1
  const long hoff = (long)h * 64;
  const f4 z4 = {0.f,0.f,0.f,0.f};

  bfrag bqv[2];
  #pragma unroll
  for (int kk=0;kk<2;kk++)
    bqv[kk] = *(const bfrag*)(qV + ((long)(i0 + lr)*8 + b)*1024 + hoff + kk*32 + lg*8);
  bfrag aq[2];
  #pragma unroll
  for (int kk=0;kk<2;kk++)
    aq[kk] = *(const bfrag*)(qU + ((long)(i0 + lr)*8 + b)*1024 + hoff + kk*32 + lg*8);

  const int nv1 = (gmax >= w) ? (((gmax - w) >> 2) + 1) : 0;  // half1 valid prefix len

  f4 s[16];

#define LDK(DST, n_) { \
    const int cbx = c0 + (w + 4*(n_))*16; \
    DST[0] = *(const bfrag*)(kh + ((long)(cbx + lr)*8 + b)*1024 + hoff + lg*8); \
    DST[1] = *(const bfrag*)(kh + ((long)(cbx + lr)*8 + b)*1024 + hoff + 32 + lg*8); }

#define AC_CMP(n_, CUR) { \
    const int cbx = c0 + (w + 4*(n_))*16; \
    f4 a = z4; \
    __builtin_amdgcn_s_setprio(1); \
    a = __builtin_amdgcn_mfma_f32_16x16x32_bf16(aq[0], CUR[0], a, 0,0,0); \
    a = __builtin_amdgcn_mfma_f32_16x16x32_bf16(aq[1], CUR[1], a, 0,0,0); \
    __builtin_amdgcn_s_setprio(0); \
    _Pragma("unroll") \
    for (int q=0;q<4;q++){ \
      const int di = lg*4 + q; \
      const int jc = cbx + lr; \
      if (jc > i0 + di + 512) a[q] = -1e30f; \
      else { \
        const int rr = jc - di + radd; \
        a[q] += bf2f(*(const unsigned short*)(Sm + rr*38 + di*2)); \
      } \
    } \
    s[half*8 + n_] = a; }

#define AC_STEP(n_, CUR, NXT) \
    if ((n_)+2 < nv) LDK(NXT, (n_)+2); \
    if ((n_) < nv) AC_CMP(n_, CUR) \
    else s[half*8 + n_] = (f4){-1e30f,-1e30f,-1e30f,-1e30f};

  #pragma unroll
  for (int half=0; half<2; ++half){
    const int c0    = half*512;
    const int rbase = half ? (1008 - i0) : (496 - i0);
    const int ntil  = half ? (gmax + 1) : 33;
    const int radd  = half ? -497 : 15;      // rr = jc - di + radd
    // ---- band fill: BDpre^T rows rr, cols di ----
    for (int mt = w; mt < ntil; mt += 4){
      const int r0 = rbase + mt*16;
      f4 acc = z4;
      #pragma unroll
      for (int kk=0;kk<2;kk++){
        bfrag ar = *(const bfrag*)(rh + (long)(r0 + lr)*1024 + hoff + kk*32 + lg*8);
        acc = __builtin_amdgcn_mfma_f32_16x16x32_bf16(ar, bqv[kk], acc, 0,0,0);
      }
      #pragma unroll
      for (int q=0;q<4;q++){
        const int rr = mt*16 + lg*4 + q;
        *(unsigned short*)(Sm + rr*38 + lr*2) = f2bf(acc[q]);
      }
    }
    __syncthreads();
    // ---- AC + BD, 2-deep kh prefetch, valid groups form a prefix ----
    const int nv = (half==0) ? 8 : nv1;
    {
      bfrag bkA[2], bkB[2], bkC[2];
      if (0 < nv) LDK(bkA, 0);
      if (1 < nv) LDK(bkB, 1);
      AC_STEP(0, bkA, bkC)
      AC_STEP(1, bkB, bkA)
      AC_STEP(2, bkC, bkB)
      AC_STEP(3, bkA, bkC)
      AC_STEP(4, bkB, bkA)
      AC_STEP(5, bkC, bkB)
      AC_STEP(6, bkA, bkC)
      AC_STEP(7, bkB, bkA)
    }
    __syncthreads();   // all band reads done before next half / P staging
  }

  // ---- pre-issue vhT chunk 0 (hides under softmax) ----
  const unsigned short* vb_base = vhT + (long)(b*16 + h)*65536;

#define LDV(DST, t_) { \
    const int c0v = ((t_) >> 2) * 512; \
    const int tau = (t_) & 3; \
    const int jA = c0v + (w + 8*tau)*16; \
    const int jB = c0v + (w + 8*tau + 4)*16; \
    const int jcol = (lg < 2) ? (jA + lg*8) : (jB + (lg-2)*8); \
    _Pragma("unroll") \
    for (int nd=0; nd<4; nd++) \
      DST[nd] = *(const bfrag*)(vb_base + (long)(nd*16 + lr)*1024 + jcol); }

#define CHV(t_) ((t_) < 4 || (2*((t_)-4) < nv1))

  bfrag vbA[4], vbB[4];
  LDV(vbA, 0);

  // ---- softmax stats over full 1024 cols ----
  float mx[4], sum[4];
  #pragma unroll
  for (int q=0;q<4;q++){
    float m = s[0][q];
    #pragma unroll
    for (int n=1;n<16;n++) m = fmaxf(m, s[n][q]);
    m = fmaxf(m, __shfl_xor(m, 1));
    m = fmaxf(m, __shfl_xor(m, 2));
    m = fmaxf(m, __shfl_xor(m, 4));
    m = fmaxf(m, __shfl_xor(m, 8));
    if (lr == 0) redm[w][lg*4+q] = m;
  }
  __syncthreads();
  #pragma unroll
  for (int q=0;q<4;q++){
    const int row = lg*4+q;
    mx[q] = fmaxf(fmaxf(redm[0][row], redm[1][row]), fmaxf(redm[2][row], redm[3][row]));
    sum[q] = 0.0f;
  }
  #pragma unroll
  for (int n=0;n<16;n++)
    #pragma unroll
    for (int q=0;q<4;q++){
      const float e = __expf(s[n][q] - mx[q]);
      s[n][q] = e;
      sum[q] += e;
    }
  #pragma unroll
  for (int q=0;q<4;q++){
    float v = sum[q];
    v += __shfl_xor(v, 1);
    v += __shfl_xor(v, 2);
    v += __shfl_xor(v, 4);
    v += __shfl_xor(v, 8);
    if (lr == 0) reds[w][lg*4+q] = v;
  }
  __syncthreads();
  if (tid < 16)
    invd[tid] = 1.0f / (reds[0][tid] + reds[1][tid] + reds[2][tid] + reds[3][tid]);

  // ---- PV: per-wave over its valid 32-col chunks, 1-deep vhT prefetch ----
  f4 oac[4];
  #pragma unroll
  for (int nd=0;nd<4;nd++) oac[nd] = z4;
  char* Pch = Sm + w*1024;            // [16 rows][32 cols] u16, swizzled

#define PV_STEP(t_, CUR, NXT) \
    if ((t_)+1 < 8 && CHV((t_)+1)) LDV(NXT, (t_)+1); \
    if (CHV(t_)){ \
      const int s0i = (((t_)<4)?0:8) + ((t_)&3)*2; \
      _Pragma("unroll") \
      for (int nn=0;nn<2;nn++){ \
        const f4 e = s[s0i + nn]; \
        _Pragma("unroll") \
        for (int q=0;q<4;q++){ \
          const int row = lg*4 + q; \
          const int col = nn*16 + lr; \
          *(unsigned short*)(Pch + row*64 + ((col*2) ^ (((row>>2)&3)<<4))) = f2bf(e[q]); \
        } \
      } \
      bfrag pa = *(const bfrag*)(Pch + lr*64 + ((lg*16) ^ (((lr>>2)&3)<<4))); \
      __builtin_amdgcn_s_setprio(1); \
      _Pragma("unroll") \
      for (int nd=0;nd<4;nd++) \
        oac[nd] = __builtin_amdgcn_mfma_f32_16x16x32_bf16(pa, CUR[nd], oac[nd], 0,0,0); \
      __builtin_amdgcn_s_setprio(0); \
    }

  PV_STEP(0, vbA, vbB)
  PV_STEP(1, vbB, vbA)
  PV_STEP(2, vbA, vbB)
  PV_STEP(3, vbB, vbA)
  PV_STEP(4, vbA, vbB)
  PV_STEP(5, vbB, vbA)
  PV_STEP(6, vbA, vbB)
  PV_STEP(7, vbB, vbA)

  // partial O to LDS
  float* po = (float*)(Sm + 4096 + w*4096);   // [16][64] f32
  #pragma unroll
  for (int nd=0;nd<4;nd++)
    #pragma unroll
    for (int q=0;q<4;q++)
      po[(lg*4+q)*64 + nd*16 + lr] = oac[nd][q];
  __syncthreads();
  // ---- merge + normalize + write ----
  {
    const int row = tid >> 4;
    const int d0  = (tid & 15) * 4;
    f4 v = *(const f4*)(Sm + 4096 + (row*64 + d0)*4);
    #pragma unroll
    for (int ww=1;ww<4;ww++){
      const f4 u = *(const f4*)(Sm + 4096 + ww*4096 + (row*64 + d0)*4);
      v.x += u.x; v.y += u.y; v.z += u.z; v.w += u.w;
    }
    const float iv = invd[row];
    u16x4 o;
    o.x = f2bf(v.x*iv); o.y = f2bf(v.y*iv); o.z = f2bf(v.z*iv); o.w = f2bf(v.w*iv);
    *(u16x4*)(ctx + ((long)(i0 + row)*8 + b)*1024 + hoff + d0) = o;
  }
#undef LDK
#undef AC_CMP
#undef AC_STEP
#undef LDV
#undef CHV
#undef PV_STEP
}

// ---------------------------------------------------------------------------
// LayerNorm: rows < splitRow read f32 srcA; rows >= splitRow read bf16 srcB.
__global__ __launch_bounds__(256) void ln_k(const float* __restrict__ srcA,
                                            const unsigned short* __restrict__ srcB, int splitRow,
                                            const float* __restrict__ g, const float* __restrict__ b,
                                            unsigned short* __restrict__ dst){
  const int row = blockIdx.x;
  const int t = threadIdx.x;
  float4 v;
  if (row < splitRow){
    v = ((const float4*)(srcA + (long)row*1024))[t];
  } else {
    u16x4 uv = *(const u16x4*)(srcB + (long)(row - splitRow)*1024 + t*4);
    v.x = bf2f(uv.x); v.y = bf2f(uv.y); v.z = bf2f(uv.z); v.w = bf2f(uv.w);
  }
  float s1 = v.x+v.y+v.z+v.w;
  float s2 = v.x*v.x+v.y*v.y+v.z*v.z+v.w*v.w;
  #pragma unroll
  for (int o=32;o;o>>=1){ s1 += __shfl_xor(s1,o); s2 += __shfl_xor(s2,o); }
  __shared__ float r1[4], r2[4];
  const int w = t>>6;
  if ((t&63)==0){ r1[w]=s1; r2[w]=s2; }
  __syncthreads();
  s1 = r1[0]+r1[1]+r1[2]+r1[3];
  s2 = r2[0]+r2[1]+r2[2]+r2[3];
  const float mean = s1*(1.0f/1024.0f);
  const float var  = s2*(1.0f/1024.0f) - mean*mean;
  const float rs   = rsqrtf(var + 1e-5f);
  float4 gg = ((const float4*)g)[t];
  float4 bb = ((const float4*)b)[t];
  u16x4 o;
  o.x = f2bf((v.x-mean)*rs*gg.x + bb.x);
  o.y = f2bf((v.y-mean)*rs*gg.y + bb.y);
  o.z = f2bf((v.z-mean)*rs*gg.z + bb.z);
  o.w = f2bf((v.w-mean)*rs*gg.w + bb.w);
  *(u16x4*)(dst + (long)row*1024 + t*4) = o;
}

__global__ __launch_bounds__(256) void conv_k(const float* __restrict__ s,
                                              unsigned short* __restrict__ d, long n){
  long i = ((long)blockIdx.x*256 + threadIdx.x)*4;
  if (i >= n) return;
  float4 v = *(const float4*)(s + i);
  u16x4 o; o.x=f2bf(v.x); o.y=f2bf(v.y); o.z=f2bf(v.z); o.w=f2bf(v.w);
  *(u16x4*)(d + i) = o;
}

// one launch converts all 5 weight blocks of a layer into contiguous wb0
__global__ __launch_bounds__(256) void conv5_k(const float* __restrict__ wat,
                                               const float* __restrict__ g1,
                                               const float* __restrict__ g2,
                                               const float* __restrict__ f1,
                                               const float* __restrict__ f2,
                                               unsigned short* __restrict__ dst){
  const long i = ((long)blockIdx.x*256 + threadIdx.x)*4;   // < 26214400
  const float* s; long off;
  if      (i <  5242880){ s = wat; off = 0; }
  else if (i < 11534336){ s = g1;  off = 5242880; }
  else if (i < 17825792){ s = g2;  off = 11534336; }
  else if (i < 22020096){ s = f1;  off = 17825792; }
  else                  { s = f2;  off = 22020096; }
  float4 v = *(const float4*)(s + (i - off));
  u16x4 o; o.x=f2bf(v.x); o.y=f2bf(v.y); o.z=f2bf(v.z); o.w=f2bf(v.w);
  *(u16x4*)(dst + i) = o;
}

__global__ __launch_bounds__(128) void ht_k(const float* __restrict__ h,
                                            unsigned short* __restrict__ d){
  const int row = blockIdx.x;           // i*8+b
  const int i = row>>3, b = row&7;
  const float* src = h + ((long)b*512 + i)*512;
  const int t = threadIdx.x;
  float4 v = ((const float4*)src)[t];
  u16x4 o; o.x=f2bf(v.x); o.y=f2bf(v.y); o.z=f2bf(v.z); o.w=f2bf(v.w);
  *(u16x4*)(d + (long)row*512 + t*4) = o;
}

__global__ __launch_bounds__(256) void pos_k(unsigned short* __restrict__ d){
  const int r = blockIdx.x, t = threadIdx.x;
  const float seq = (float)(1023 - r);
  u16x4 o;
  #pragma unroll
  for (int q=0;q<4;q++){
    const int c = t*4 + q;
    const int f = (c < 512) ? c : (c - 512);
    const float inv = expf((float)f * -0.017988946039016f); // -2*ln(1e4)/1024
    const float ang = seq * inv;
    const float val = (c < 512) ? sinf(ang) : cosf(ang);
    o[q] = f2bf(val);
  }
  *(u16x4*)(d + (long)r*1024 + t*4) = o;
}

// ---------------------------------------------------------------------------
extern "C" void kernel_launch(void* const* d_in, const int* in_sizes, int n_in,
                              void* d_out, int out_size, void* d_ws, size_t ws_size,
                              hipStream_t stream){
  (void)in_sizes; (void)n_in; (void)out_size; (void)ws_size;
  const float* h     = (const float*)d_in[0];
  const float* memin = (const float*)d_in[1];
  const float* Wemb  = (const float*)d_in[2];
  const float* bemb  = (const float*)d_in[3];
  const float* Ub    = (const float*)d_in[4];
  const float* Vb    = (const float*)d_in[5];
  const float* ln1   = (const float*)d_in[6];
  const float* ln2   = (const float*)d_in[7];
  const float* Wattn = (const float*)d_in[8];
  const float* g1w   = (const float*)d_in[9];
  const float* g2w   = (const float*)d_in[10];
  const float* fw1   = (const float*)d_in[11];
  const float* fb1   = (const float*)d_in[12];
  const float* fw2   = (const float*)d_in[13];
  const float* fb2   = (const float*)d_in[14];

  char* Wp = (char*)d_ws;
  size_t off = 0;
  auto take = [&](size_t bytes)->size_t{ size_t r = off; off += (bytes + 255) & ~(size_t)255; return r; };
  unsigned short* xbf  = (unsigned short*)(Wp + take( 8388608)); // out bf16
  unsigned short* o1b  = (unsigned short*)(Wp + take( 8388608)); // gru1 out bf16
  unsigned short* zbb  = (unsigned short*)(Wp + take( 8388608)); // gru z-gate bf16
  unsigned short* rxb  = (unsigned short*)(Wp + take( 8388608)); // r*x bf16
  unsigned short* yb   = (unsigned short*)(Wp + take( 8388608)); // Y / E2 bf16
  unsigned short* Eb   = (unsigned short*)(Wp + take( 8388608)); // LN2 out bf16
  unsigned short* wb0  = (unsigned short*)(Wp + take(52428800)); // layer weights bf16
  unsigned short* hTb  = (unsigned short*)(Wp + take( 4194304));
  unsigned short* webb = (unsigned short*)(Wp + take( 1048576));
  unsigned short* posb = (unsigned short*)(Wp + take( 2097152));
  unsigned short* nkb  = (unsigned short*)(Wp + take(16777216)); // LN'd key (full*bs, D)
  unsigned short* qUb  = (unsigned short*)(Wp + take( 8388608));
  unsigned short* qVb  = (unsigned short*)(Wp + take( 8388608));
  unsigned short* khb  = (unsigned short*)(Wp + take(16777216));
  unsigned short* vhTb = (unsigned short*)(Wp + take(16777216));
  unsigned short* F1b  = khb; // FF hidden (32MB) overlaps khb+vhTb (phase-disjoint)
  unsigned short* rhb  = (unsigned short*)(Wp + take( 2097152));
  unsigned short* ctxb = (unsigned short*)(Wp + take( 8388608));

  const int M1 = 1048576; // D*D elements

  // one-time prep
  conv_k<<<512, 256, 0, stream>>>(Wemb, webb, 524288);
  ht_k<<<4096, 128, 0, stream>>>(h, hTb);
  pos_k<<<1024, 256, 0, stream>>>(posb);

  { // embed: out = gelu(h @ Wemb^T + bemb)  (bf16)
    GP p{}; p.A=hTb; p.B=webb; p.O1=xbf; p.bias1=bemb;
    p.K=512; p.lda=512; p.ldb=512; p.ldo=1024;
    gemm_k<128,64,6><<<dim3(16,32,1),256,0,stream>>>(p);
  }

  // GRU (2 launches, K=2048 concat): x=xb, y=yb_, weights w6 = [Wr,Ur,Wz,Uz,Wg,Ug]
  // last=true: final-layer combine writes f32 transposed directly to d_out.
  auto gru_fn = [&](const unsigned short* xb, const unsigned short* yb_,
                    const unsigned short* w6, unsigned short* ob, float* of, bool last){
    { GP p{}; p.A=yb_; p.A2=xb; p.B=w6; p.B2=w6+M1; p.sBz=2*M1;
      p.O1=rxb; p.O2=zbb; p.XB=xb;
      p.K=2048; p.Ksplit=1024; p.lda=1024; p.ldb=1024; p.ldo=1024;
      gemm_k<128,64,11><<<dim3(16,32,2),256,0,stream>>>(p); }
    GP p{}; p.A=yb_; p.A2=rxb; p.B=w6+4*M1; p.B2=w6+5*M1;
    p.XB=xb; p.ZB=zbb; p.O1=ob; p.OF=of;
    p.K=2048; p.Ksplit=1024; p.lda=1024; p.ldb=1024; p.ldo=1024;
    if (last) gemm_k<128,64,14><<<dim3(16,32,1),256,0,stream>>>(p);
    else      gemm_k<128,64,12><<<dim3(16,32,1),256,0,stream>>>(p);
  };

  for (int l = 0; l < 4; ++l){
    // layer weights -> bf16 (single merged launch: 25600 blocks)
    conv5_k<<<25600,256,0,stream>>>(Wattn + (long)l*5242880,
                                    g1w   + (long)l*6291456,
                                    g2w   + (long)l*6291456,
                                    fw1   + (long)l*4194304,
                                    fw2   + (long)l*4194304, wb0);

    // nk = LN(concat(mem[l] f32, out bf16)); rows [4096:8192) are nq
    ln_k<<<8192,256,0,stream>>>(memin + (long)l*4194304, xbf, 4096,
                                ln1 + l*2048, ln1 + l*2048 + 1024, nkb);

    { // fused QKV + R: z=0 kh, z=1 vhT, z=2 qU/qV (*0.125), z=3 rh
      GP p{}; p.A=nkb; p.A2=posb; p.B=wb0;
      p.O1=khb; p.O2=vhTb; p.O3=qUb; p.O4=qVb; p.O5=rhb;
      p.bias1=Ub; p.bias2=Vb;
      p.K=1024; p.lda=1024; p.ldb=1024; p.ldo=1024;
      gemm_k<128,64,13><<<dim3(16,64,4),256,0,stream>>>(p); }

    attn_k<<<4096,256,0,stream>>>(qUb, qVb, khb, rhb, vhTb, ctxb);

    { // Y = gelu(ctx @ Wo^T)
      GP p{}; p.A=ctxb; p.B=wb0+4*M1; p.O1=yb;
      p.K=1024; p.lda=1024; p.ldb=1024; p.ldo=1024;
      gemm_k<128,64,6><<<dim3(16,32,1),256,0,stream>>>(p); }

    gru_fn(xbf, yb, wb0 + 5*M1, o1b, nullptr, false);

    ln_k<<<4096,256,0,stream>>>(nullptr, o1b, 0,
                                ln2 + l*2048, ln2 + l*2048 + 1024, Eb);

    { GP p{}; p.A=Eb;  p.B=wb0+17*M1; p.O1=F1b; p.bias1=fb1 + l*4096;
      p.K=1024; p.lda=1024; p.ldb=1024; p.ldo=4096;
      gemm_k<128,64,6><<<dim3(64,32,1),256,0,stream>>>(p); }
    { GP p{}; p.A=F1b; p.B=wb0+21*M1; p.O1=yb; p.bias1=fb2 + l*1024;
      p.K=4096; p.lda=4096; p.ldb=4096; p.ldo=1024;
      gemm_k<128,64,6><<<dim3(16,32,1),256,0,stream>>>(p); }

    gru_fn(o1b, yb, wb0 + 11*M1, xbf, (float*)d_out, l==3);
  }
}

// Round 12
// 2782.004 us; speedup vs baseline: 1.1711x; 1.1711x over previous
//
#include <hip/hip_runtime.h>
#include <hip/hip_bf16.h>

// Gated Transformer-XL forward.
// Dims: L=4, D=1024, NH=16, HD=64, CUR=512, MEM=512, BS=8, IN=512, FF=4096, FULL=1024
// Activation layout: (seq*BS, D), row = i*BS + b. All activations bf16.

typedef __attribute__((ext_vector_type(8))) __bf16 bfrag;
typedef __attribute__((ext_vector_type(4))) float f4;
typedef __attribute__((ext_vector_type(4))) unsigned short u16x4;
typedef __attribute__((ext_vector_type(8))) unsigned short u16x8;

__device__ __forceinline__ unsigned short f2bf(float f){
  union { float f; unsigned u; } v; v.f = f;
  unsigned r = v.u + 0x7fffu + ((v.u >> 16) & 1u);
  return (unsigned short)(r >> 16);
}
__device__ __forceinline__ float bf2f(unsigned short u){
  union { unsigned u; float f; } v; v.u = (unsigned)u << 16; return v.f;
}
__device__ __forceinline__ float geluf(float x){
  return 0.5f * x * (1.0f + erff(x * 0.7071067811865476f));
}
__device__ __forceinline__ float sigm(float x){ return 1.0f/(1.0f + __expf(-x)); }

__device__ __forceinline__ void gl_lds(const void* g, void* l){
  __builtin_amdgcn_global_load_lds(
    reinterpret_cast<const __attribute__((address_space(1))) unsigned int*>(
        reinterpret_cast<unsigned long>(g)),
    reinterpret_cast<__attribute__((address_space(3))) unsigned int*>(
        reinterpret_cast<unsigned long>(l)),
    16, 0, 0);
}

// ---------------------------------------------------------------------------
// Dense GEMM: C[M,N] = A[M,K] @ B[N,K]^T (bf16, row-major). Optional K-concat.
// Ring-4 counted-vmcnt pipeline (BK=32 steps): at step j issue loads for
// buf[j+2] (3/thread), s_waitcnt vmcnt(6) (buf[j]'s 3 loads retired — FIFO),
// RAW s_barrier (no drain), compute buf[j]. TAIL DRAIN (round-11 bug fix):
// j=nk-2 -> vmcnt(3), j=nk-1 -> vmcnt(0) (no new stage issued, so the
// counted wait must shrink or buf[j]'s loads are NOT retired).
// All instantiations BM=128/BN=64 -> 3 loads/stage -> constants everywhere.
// EPI: 6  O1 = bf(gelu(acc + bias1))
//      11 z==0: O1 = bf(sigm(acc) * XB)  (GRU r-gate * x) | z==1: O2 = bf(sigm(acc-2))
//      12 o = (1-Z)*X + Z*tanh(acc); O1 = bf(o)            (GRU combine)
//      14 as 12 but OF[d_out] = o, f32, (b,i)-transposed   (final layer)
//      13 fused QKV+R: z=0 kh, z=1 vhT-scatter, z=2 qU/qV(+bias, *0.125), z=3 rh
// ---------------------------------------------------------------------------
struct GP {
  const unsigned short* A;
  const unsigned short* A2;
  const unsigned short* B;
  const unsigned short* B2;
  unsigned short* O1;
  unsigned short* O2;
  unsigned short* O3;
  unsigned short* O4;
  unsigned short* O5;
  float* OF;
  const float* bias1;
  const float* bias2;
  const unsigned short* XB;
  const unsigned short* ZB;
  int K, Ksplit, lda, ldb, ldo;
  int sBz;
};

template<int BM, int BN, int EPI>
__global__ __launch_bounds__(256) void gemm_k(GP p){
  __shared__ unsigned short As[4][BM*32];
  __shared__ unsigned short Bs[4][BN*32];
  const int tid  = threadIdx.x;
  const int lane = tid & 63;
  const int wid  = tid >> 6;
  const int lr   = lane & 15;
  const int lg   = lane >> 4;
  constexpr int FM = BM/32, FN = BN/32;

  // XCD swizzle (bijective; all grids have nwg%8==0)
  int bx = blockIdx.x, by = blockIdx.y;
  {
    const int gx = gridDim.x;
    const int nwg = gx * gridDim.y;
    if ((nwg & 7) == 0){
      const int bid = by*gx + bx;
      const int vid = (bid & 7)*(nwg >> 3) + (bid >> 3);
      bx = vid % gx;
      by = vid / gx;
    }
  }
  const int m0 = by * BM;
  const int n0 = bx * BN;
  const int z  = blockIdx.z;

  const unsigned short* Abase = p.A;
  const unsigned short* Bbase = p.B;
  if constexpr (EPI==13){
    if (z==2){ if (by >= 32) return; Abase = p.A + 4194304; }
    if (z==3){ if (by >= 8)  return; Abase = p.A2; }
    const int zsel = (z==0)?1:((z==1)?2:((z==2)?0:3));
    Bbase = p.B + (long)zsel*1048576;
  }

  const int ksp = p.Ksplit ? p.Ksplit : p.K;
  const unsigned short* AbL = Abase + (long)m0*p.lda;
  const unsigned short* AbH = p.A2 && EPI!=13 ? (p.A2 + (long)m0*p.lda - ksp) : AbL;
  const unsigned short* BbL = Bbase + (long)z*p.sBz + (long)n0*p.ldb;
  const unsigned short* BbH = p.B2 ? (p.B2 + (long)z*p.sBz + (long)n0*p.ldb - ksp) : BbL;

  const int srow = tid >> 2;          // 0..63
  const int skk  = (tid & 3) * 8;

  f4 acc[FM][FN];
  f4 zero4 = {0.0f, 0.0f, 0.0f, 0.0f};
  #pragma unroll
  for (int m=0;m<FM;m++)
    #pragma unroll
    for (int n=0;n<FN;n++) acc[m][n] = zero4;

  auto stage = [&](int buf, int k0){
    const unsigned short* A_ = (k0 < ksp) ? AbL : AbH;
    #pragma unroll
    for (int q=0;q<BM/64;q++)
      gl_lds(A_ + (long)(q*64 + srow)*p.lda + k0 + skk, (char*)As[buf] + q*4096 + wid*1024);
    const unsigned short* B_ = (k0 < ksp) ? BbL : BbH;
    #pragma unroll
    for (int q=0;q<BN/64;q++)
      gl_lds(B_ + (long)(q*64 + srow)*p.ldb + k0 + skk, (char*)Bs[buf] + q*4096 + wid*1024);
  };

  const int nk = p.K >> 5;            // 32-K steps; nk >= 16 for all our shapes
  stage(0, 0);
  stage(1, 32);

  for (int j = 0; j < nk; ++j){
    if (j+2 < nk){
      stage((j+2)&3, (j+2)<<5);
      asm volatile("s_waitcnt vmcnt(6)" ::: "memory");  // retire buf[j]'s 3 (9 outstanding)
    } else if (j+1 < nk){
      asm volatile("s_waitcnt vmcnt(3)" ::: "memory");  // 6 outstanding: retire buf[nk-2]'s 3
    } else {
      asm volatile("s_waitcnt vmcnt(0)" ::: "memory");  // 3 outstanding: retire buf[nk-1]'s 3
    }
    __builtin_amdgcn_sched_barrier(0);
    __builtin_amdgcn_s_barrier();                       // raw: no vmcnt(0) drain
    __builtin_amdgcn_sched_barrier(0);
    const int cb = j & 3;
    bfrag af[FM], bfr[FN];
    #pragma unroll
    for (int m=0;m<FM;m++)
      af[m] = *(const bfrag*)&As[cb][((wid>>1)*(BM/2) + m*16 + lr)*32 + lg*8];
    #pragma unroll
    for (int n=0;n<FN;n++)
      bfr[n] = *(const bfrag*)&Bs[cb][((wid&1)*(BN/2) + n*16 + lr)*32 + lg*8];
    #pragma unroll
    for (int m=0;m<FM;m++)
      #pragma unroll
      for (int n=0;n<FN;n++)
        acc[m][n] = __builtin_amdgcn_mfma_f32_16x16x32_bf16(af[m], bfr[n], acc[m][n], 0, 0, 0);
  }

  const int wr0 = m0 + (wid>>1)*(BM/2);
  const int wc0 = n0 + (wid&1)*(BN/2);
  #pragma unroll
  for (int m=0;m<FM;m++)
    #pragma unroll
    for (int n=0;n<FN;n++)
      #pragma unroll
      for (int r=0;r<4;r++){
        const int gr = wr0 + m*16 + lg*4 + r;
        const int gc = wc0 + n*16 + lr;
        const float a = acc[m][n][r];
        const long base = (long)gr*p.ldo + gc;
        if constexpr (EPI==6){
          const float t = a + (p.bias1 ? p.bias1[gc] : 0.0f);
          p.O1[base] = f2bf(geluf(t));
        }
        else if constexpr (EPI==11){
          const long ix = (long)gr*1024 + gc;
          if (z==0) p.O1[ix] = f2bf(sigm(a) * bf2f(p.XB[ix]));
          else      p.O2[ix] = f2bf(sigm(a - 2.0f));
        }
        else if constexpr (EPI==12){
          const long ix = (long)gr*1024 + gc;
          const float zz = bf2f(p.ZB[ix]);
          const float oo = (1.0f - zz)*bf2f(p.XB[ix]) + zz*tanhf(a);
          p.O1[ix] = f2bf(oo);
        }
        else if constexpr (EPI==14){
          const long ix = (long)gr*1024 + gc;
          const float zz = bf2f(p.ZB[ix]);
          const float oo = (1.0f - zz)*bf2f(p.XB[ix]) + zz*tanhf(a);
          const int i_ = gr >> 3, b_ = gr & 7;
          p.OF[(long)b_*524288 + (long)i_*1024 + gc] = oo;
        }
        else if constexpr (EPI==13){
          const long ix = (long)gr*1024 + gc;
          if (z==0){ p.O1[ix] = f2bf(a); }
          else if (z==1){
            const int b_ = gr & 7, js = gr >> 3, h_ = gc >> 6, d_ = gc & 63;
            p.O2[(long)(b_*16 + h_)*65536 + (long)d_*1024 + js] = f2bf(a);
          }
          else if (z==2){ p.O3[ix] = f2bf((a + p.bias1[gc])*0.125f);
                          p.O4[ix] = f2bf((a + p.bias2[gc])*0.125f); }
          else { p.O5[ix] = f2bf(a); }
        }
      }
}

// ---------------------------------------------------------------------------
// Fused relative attention (round-9 exact: 256,3; VGPR 84, no spill).
// Any launch_bounds >3 spills this body (rounds 4/6/10 evidence).
// ---------------------------------------------------------------------------
__global__ __launch_bounds__(256,3) void attn_k(const unsigned short* __restrict__ qU,
                                                const unsigned short* __restrict__ qV,
                                                const unsigned short* __restrict__ kh,
                                                const unsigned short* __restrict__ rh,
                                                const unsigned short* __restrict__ vhT,
                                                unsigned short* __restrict__ ctx){
  __shared__ char Sm[20480];          // band (528*38=20064) / P-chunks (4KB) / po @4096 (16KB)
  __shared__ float redm[4][16];
  __shared__ float reds[4][16];
  __shared__ float invd[16];
  const int tid = threadIdx.x;
  const int w   = tid >> 6;
  const int lane= tid & 63;
  const int lr  = lane & 15;
  const int lg  = lane >> 4;
  const int id = blockIdx.x;
  const int b  = id & 7;              // id%8 -> XCD: per-b kh/vhT slice stays in one L2
  const int i0 = ((id >> 3) & 31) * 16;
  const int h  = id >> 8;
  const int gmax = i0 >> 4;           // last valid 16-col group in half1
  const long hoff = (long)h * 64;
  const f4 z4 = {0.f,0.f,0.f,0.f};

  bfrag bqv[2];
  #pragma unroll
  for (int kk=0;kk<2;kk++)
    bqv[kk] = *(const bfrag*)(qV + ((long)(i0 + lr)*8 + b)*1024 + hoff + kk*32 + lg*8);
  bfrag aq[2];
  #pragma unroll
  for (int kk=0;kk<2;kk++)
    aq[kk] = *(const bfrag*)(qU + ((long)(i0 + lr)*8 + b)*1024 + hoff + kk*32 + lg*8);

  const int nv1 = (gmax >= w) ? (((gmax - w) >> 2) + 1) : 0;  // half1 valid prefix len

  f4 s[16];

#define LDK(DST, n_) { \
    const int cbx = c0 + (w + 4*(n_))*16; \
    DST[0] = *(const bfrag*)(kh + ((long)(cbx + lr)*8 + b)*1024 + hoff + lg*8); \
    DST[1] = *(const bfrag*)(kh + ((long)(cbx + lr)*8 + b)*1024 + hoff + 32 + lg*8); }

#define AC_CMP(n_, CUR) { \
    const int cbx = c0 + (w + 4*(n_))*16; \
    f4 a = z4; \
    __builtin_amdgcn_s_setprio(1); \
    a = __builtin_amdgcn_mfma_f32_16x16x32_bf16(aq[0], CUR[0], a, 0,0,0); \
    a = __builtin_amdgcn_mfma_f32_16x16x32_bf16(aq[1], CUR[1], a, 0,0,0); \
    __builtin_amdgcn_s_setprio(0); \
    _Pragma("unroll") \
    for (int q=0;q<4;q++){ \
      const int di = lg*4 + q; \
      const int jc = cbx + lr; \
      if (jc > i0 + di + 512) a[q] = -1e30f; \
      else { \
        const int rr = jc - di + radd; \
        a[q] += bf2f(*(const unsigned short*)(Sm + rr*38 + di*2)); \
      } \
    } \
    s[half*8 + n_] = a; }

#define AC_STEP(n_, CUR, NXT) \
    if ((n_)+2 < nv) LDK(NXT, (n_)+2); \
    if ((n_) < nv) AC_CMP(n_, CUR) \
    else s[half*8 + n_] = (f4){-1e30f,-1e30f,-1e30f,-1e30f};

  #pragma unroll
  for (int half=0; half<2; ++half){
    const int c0    = half*512;
    const int rbase = half ? (1008 - i0) : (496 - i0);
    const int ntil  = half ? (gmax + 1) : 33;
    const int radd  = half ? -497 : 15;      // rr = jc - di + radd
    // ---- band fill: BDpre^T rows rr, cols di ----
    for (int mt = w; mt < ntil; mt += 4){
      const int r0 = rbase + mt*16;
      f4 acc = z4;
      #pragma unroll
      for (int kk=0;kk<2;kk++){
        bfrag ar = *(const bfrag*)(rh + (long)(r0 + lr)*1024 + hoff + kk*32 + lg*8);
        acc = __builtin_amdgcn_mfma_f32_16x16x32_bf16(ar, bqv[kk], acc, 0,0,0);
      }
      #pragma unroll
      for (int q=0;q<4;q++){
        const int rr = mt*16 + lg*4 + q;
        *(unsigned short*)(Sm + rr*38 + lr*2) = f2bf(acc[q]);
      }
    }
    __syncthreads();
    // ---- AC + BD, 2-deep kh prefetch, valid groups form a prefix ----
    const int nv = (half==0) ? 8 : nv1;
    {
      bfrag bkA[2], bkB[2], bkC[2];
      if (0 < nv) LDK(bkA, 0);
      if (1 < nv) LDK(bkB, 1);
      AC_STEP(0, bkA, bkC)
      AC_STEP(1, bkB, bkA)
      AC_STEP(2, bkC, bkB)
      AC_STEP(3, bkA, bkC)
      AC_STEP(4, bkB, bkA)
      AC_STEP(5, bkC, bkB)
      AC_STEP(6, bkA, bkC)
      AC_STEP(7, bkB, bkA)
    }
    __syncthreads();   // all band reads done before next half / P staging
  }

  // ---- pre-issue vhT chunk 0 (hides under softmax) ----
  const unsigned short* vb_base = vhT + (long)(b*16 + h)*65536;

#define LDV(DST, t_) { \
    const int c0v = ((t_) >> 2) * 512; \
    const int tau = (t_) & 3; \
    const int jA = c0v + (w + 8*tau)*16; \
    const int jB = c0v + (w + 8*tau + 4)*16; \
    const int jcol = (lg < 2) ? (jA + lg*8) : (jB + (lg-2)*8); \
    _Pragma("unroll") \
    for (int nd=0; nd<4; nd++) \
      DST[nd] = *(const bfrag*)(vb_base + (long)(nd*16 + lr)*1024 + jcol); }

#define CHV(t_) ((t_) < 4 || (2*((t_)-4) < nv1))

  bfrag vbA[4], vbB[4];
  LDV(vbA, 0);

  // ---- softmax stats over full 1024 cols ----
  float mx[4], sum[4];
  #pragma unroll
  for (int q=0;q<4;q++){
    float m = s[0][q];
    #pragma unroll
    for (int n=1;n<16;n++) m = fmaxf(m, s[n][q]);
    m = fmaxf(m, __shfl_xor(m, 1));
    m = fmaxf(m, __shfl_xor(m, 2));
    m = fmaxf(m, __shfl_xor(m, 4));
    m = fmaxf(m, __shfl_xor(m, 8));
    if (lr == 0) redm[w][lg*4+q] = m;
  }
  __syncthreads();
  #pragma unroll
  for (int q=0;q<4;q++){
    const int row = lg*4+q;
    mx[q] = fmaxf(fmaxf(redm[0][row], redm[1][row]), fmaxf(redm[2][row], redm[3][row]));
    sum[q] = 0.0f;
  }
  #pragma unroll
  for (int n=0;n<16;n++)
    #pragma unroll
    for (int q=0;q<4;q++){
      const float e = __expf(s[n][q] - mx[q]);
      s[n][q] = e;
      sum[q] += e;
    }
  #pragma unroll
  for (int q=0;q<4;q++){
    float v = sum[q];
    v += __shfl_xor(v, 1);
    v += __shfl_xor(v, 2);
    v += __shfl_xor(v, 4);
    v += __shfl_xor(v, 8);
    if (lr == 0) reds[w][lg*4+q] = v;
  }
  __syncthreads();
  if (tid < 16)
    invd[tid] = 1.0f / (reds[0][tid] + reds[1][tid] + reds[2][tid] + reds[3][tid]);

  // ---- PV: per-wave over its valid 32-col chunks, 1-deep vhT prefetch ----
  f4 oac[4];
  #pragma unroll
  for (int nd=0;nd<4;nd++) oac[nd] = z4;
  char* Pch = Sm + w*1024;            // [16 rows][32 cols] u16, swizzled

#define PV_STEP(t_, CUR, NXT) \
    if ((t_)+1 < 8 && CHV((t_)+1)) LDV(NXT, (t_)+1); \
    if (CHV(t_)){ \
      const int s0i = (((t_)<4)?0:8) + ((t_)&3)*2; \
      _Pragma("unroll") \
      for (int nn=0;nn<2;nn++){ \
        const f4 e = s[s0i + nn]; \
        _Pragma("unroll") \
        for (int q=0;q<4;q++){ \
          const int row = lg*4 + q; \
          const int col = nn*16 + lr; \
          *(unsigned short*)(Pch + row*64 + ((col*2) ^ (((row>>2)&3)<<4))) = f2bf(e[q]); \
        } \
      } \
      bfrag pa = *(const bfrag*)(Pch + lr*64 + ((lg*16) ^ (((lr>>2)&3)<<4))); \
      __builtin_amdgcn_s_setprio(1); \
      _Pragma("unroll") \
      for (int nd=0;nd<4;nd++) \
        oac[nd] = __builtin_amdgcn_mfma_f32_16x16x32_bf16(pa, CUR[nd], oac[nd], 0,0,0); \
      __builtin_amdgcn_s_setprio(0); \
    }

  PV_STEP(0, vbA, vbB)
  PV_STEP(1, vbB, vbA)
  PV_STEP(2, vbA, vbB)
  PV_STEP(3, vbB, vbA)
  PV_STEP(4, vbA, vbB)
  PV_STEP(5, vbB, vbA)
  PV_STEP(6, vbA, vbB)
  PV_STEP(7, vbB, vbA)

  // partial O to LDS
  float* po = (float*)(Sm + 4096 + w*4096);   // [16][64] f32
  #pragma unroll
  for (int nd=0;nd<4;nd++)
    #pragma unroll
    for (int q=0;q<4;q++)
      po[(lg*4+q)*64 + nd*16 + lr] = oac[nd][q];
  __syncthreads();
  // ---- merge + normalize + write ----
  {
    const int row = tid >> 4;
    const int d0  = (tid & 15) * 4;
    f4 v = *(const f4*)(Sm + 4096 + (row*64 + d0)*4);
    #pragma unroll
    for (int ww=1;ww<4;ww++){
      const f4 u = *(const f4*)(Sm + 4096 + ww*4096 + (row*64 + d0)*4);
      v.x += u.x; v.y += u.y; v.z += u.z; v.w += u.w;
    }
    const float iv = invd[row];
    u16x4 o;
    o.x = f2bf(v.x*iv); o.y = f2bf(v.y*iv); o.z = f2bf(v.z*iv); o.w = f2bf(v.w*iv);
    *(u16x4*)(ctx + ((long)(i0 + row)*8 + b)*1024 + hoff + d0) = o;
  }
#undef LDK
#undef AC_CMP
#undef AC_STEP
#undef LDV
#undef CHV
#undef PV_STEP
}

// ---------------------------------------------------------------------------
// LayerNorm: rows < splitRow read f32 srcA; rows >= splitRow read bf16 srcB.
__global__ __launch_bounds__(256) void ln_k(const float* __restrict__ srcA,
                                            const unsigned short* __restrict__ srcB, int splitRow,
                                            const float* __restrict__ g, const float* __restrict__ b,
                                            unsigned short* __restrict__ dst){
  const int row = blockIdx.x;
  const int t = threadIdx.x;
  float4 v;
  if (row < splitRow){
    v = ((const float4*)(srcA + (long)row*1024))[t];
  } else {
    u16x4 uv = *(const u16x4*)(srcB + (long)(row - splitRow)*1024 + t*4);
    v.x = bf2f(uv.x); v.y = bf2f(uv.y); v.z = bf2f(uv.z); v.w = bf2f(uv.w);
  }
  float s1 = v.x+v.y+v.z+v.w;
  float s2 = v.x*v.x+v.y*v.y+v.z*v.z+v.w*v.w;
  #pragma unroll
  for (int o=32;o;o>>=1){ s1 += __shfl_xor(s1,o); s2 += __shfl_xor(s2,o); }
  __shared__ float r1[4], r2[4];
  const int w = t>>6;
  if ((t&63)==0){ r1[w]=s1; r2[w]=s2; }
  __syncthreads();
  s1 = r1[0]+r1[1]+r1[2]+r1[3];
  s2 = r2[0]+r2[1]+r2[2]+r2[3];
  const float mean = s1*(1.0f/1024.0f);
  const float var  = s2*(1.0f/1024.0f) - mean*mean;
  const float rs   = rsqrtf(var + 1e-5f);
  float4 gg = ((const float4*)g)[t];
  float4 bb = ((const float4*)b)[t];
  u16x4 o;
  o.x = f2bf((v.x-mean)*rs*gg.x + bb.x);
  o.y = f2bf((v.y-mean)*rs*gg.y + bb.y);
  o.z = f2bf((v.z-mean)*rs*gg.z + bb.z);
  o.w = f2bf((v.w-mean)*rs*gg.w + bb.w);
  *(u16x4*)(dst + (long)row*1024 + t*4) = o;
}

__global__ __launch_bounds__(256) void conv_k(const float* __restrict__ s,
                                              unsigned short* __restrict__ d, long n){
  long i = ((long)blockIdx.x*256 + threadIdx.x)*4;
  if (i >= n) return;
  float4 v = *(const float4*)(s + i);
  u16x4 o; o.x=f2bf(v.x); o.y=f2bf(v.y); o.z=f2bf(v.z); o.w=f2bf(v.w);
  *(u16x4*)(d + i) = o;
}

// one launch converts all 5 weight blocks of a layer into contiguous wb0
__global__ __launch_bounds__(256) void conv5_k(const float* __restrict__ wat,
                                               const float* __restrict__ g1,
                                               const float* __restrict__ g2,
                                               const float* __restrict__ f1,
                                               const float* __restrict__ f2,
                                               unsigned short* __restrict__ dst){
  const long i = ((long)blockIdx.x*256 + threadIdx.x)*4;   // < 26214400
  const float* s; long off;
  if      (i <  5242880){ s = wat; off = 0; }
  else if (i < 11534336){ s = g1;  off = 5242880; }
  else if (i < 17825792){ s = g2;  off = 11534336; }
  else if (i < 22020096){ s = f1;  off = 17825792; }
  else                  { s = f2;  off = 22020096; }
  float4 v = *(const float4*)(s + (i - off));
  u16x4 o; o.x=f2bf(v.x); o.y=f2bf(v.y); o.z=f2bf(v.z); o.w=f2bf(v.w);
  *(u16x4*)(dst + i) = o;
}

__global__ __launch_bounds__(128) void ht_k(const float* __restrict__ h,
                                            unsigned short* __restrict__ d){
  const int row = blockIdx.x;           // i*8+b
  const int i = row>>3, b = row&7;
  const float* src = h + ((long)b*512 + i)*512;
  const int t = threadIdx.x;
  float4 v = ((const float4*)src)[t];
  u16x4 o; o.x=f2bf(v.x); o.y=f2bf(v.y); o.z=f2bf(v.z); o.w=f2bf(v.w);
  *(u16x4*)(d + (long)row*512 + t*4) = o;
}

__global__ __launch_bounds__(256) void pos_k(unsigned short* __restrict__ d){
  const int r = blockIdx.x, t = threadIdx.x;
  const float seq = (float)(1023 - r);
  u16x4 o;
  #pragma unroll
  for (int q=0;q<4;q++){
    const int c = t*4 + q;
    const int f = (c < 512) ? c : (c - 512);
    const float inv = expf((float)f * -0.017988946039016f); // -2*ln(1e4)/1024
    const float ang = seq * inv;
    const float val = (c < 512) ? sinf(ang) : cosf(ang);
    o[q] = f2bf(val);
  }
  *(u16x4*)(d + (long)r*1024 + t*4) = o;
}

// ---------------------------------------------------------------------------
extern "C" void kernel_launch(void* const* d_in, const int* in_sizes, int n_in,
                              void* d_out, int out_size, void* d_ws, size_t ws_size,
                              hipStream_t stream){
  (void)in_sizes; (void)n_in; (void)out_size; (void)ws_size;
  const float* h     = (const float*)d_in[0];
  const float* memin = (const float*)d_in[1];
  const float* Wemb  = (const float*)d_in[2];
  const float* bemb  = (const float*)d_in[3];
  const float* Ub    = (const float*)d_in[4];
  const float* Vb    = (const float*)d_in[5];
  const float* ln1   = (const float*)d_in[6];
  const float* ln2   = (const float*)d_in[7];
  const float* Wattn = (const float*)d_in[8];
  const float* g1w   = (const float*)d_in[9];
  const float* g2w   = (const float*)d_in[10];
  const float* fw1   = (const float*)d_in[11];
  const float* fb1   = (const float*)d_in[12];
  const float* fw2   = (const float*)d_in[13];
  const float* fb2   = (const float*)d_in[14];

  char* Wp = (char*)d_ws;
  size_t off = 0;
  auto take = [&](size_t bytes)->size_t{ size_t r = off; off += (bytes + 255) & ~(size_t)255; return r; };
  unsigned short* xbf  = (unsigned short*)(Wp + take( 8388608)); // out bf16
  unsigned short* o1b  = (unsigned short*)(Wp + take( 8388608)); // gru1 out bf16
  unsigned short* zbb  = (unsigned short*)(Wp + take( 8388608)); // gru z-gate bf16
  unsigned short* rxb  = (unsigned short*)(Wp + take( 8388608)); // r*x bf16
  unsigned short* yb   = (unsigned short*)(Wp + take( 8388608)); // Y / E2 bf16
  unsigned short* Eb   = (unsigned short*)(Wp + take( 8388608)); // LN2 out bf16
  unsigned short* wb0  = (unsigned short*)(Wp + take(52428800)); // layer weights bf16
  unsigned short* hTb  = (unsigned short*)(Wp + take( 4194304));
  unsigned short* webb = (unsigned short*)(Wp + take( 1048576));
  unsigned short* posb = (unsigned short*)(Wp + take( 2097152));
  unsigned short* nkb  = (unsigned short*)(Wp + take(16777216)); // LN'd key (full*bs, D)
  unsigned short* qUb  = (unsigned short*)(Wp + take( 8388608));
  unsigned short* qVb  = (unsigned short*)(Wp + take( 8388608));
  unsigned short* khb  = (unsigned short*)(Wp + take(16777216));
  unsigned short* vhTb = (unsigned short*)(Wp + take(16777216));
  unsigned short* F1b  = khb; // FF hidden (32MB) overlaps khb+vhTb (phase-disjoint)
  unsigned short* rhb  = (unsigned short*)(Wp + take( 2097152));
  unsigned short* ctxb = (unsigned short*)(Wp + take( 8388608));

  const int M1 = 1048576; // D*D elements

  // one-time prep
  conv_k<<<512, 256, 0, stream>>>(Wemb, webb, 524288);
  ht_k<<<4096, 128, 0, stream>>>(h, hTb);
  pos_k<<<1024, 256, 0, stream>>>(posb);

  { // embed: out = gelu(h @ Wemb^T + bemb)  (bf16)
    GP p{}; p.A=hTb; p.B=webb; p.O1=xbf; p.bias1=bemb;
    p.K=512; p.lda=512; p.ldb=512; p.ldo=1024;
    gemm_k<128,64,6><<<dim3(16,32,1),256,0,stream>>>(p);
  }

  // GRU (2 launches, K=2048 concat): x=xb, y=yb_, weights w6 = [Wr,Ur,Wz,Uz,Wg,Ug]
  // last=true: final-layer combine writes f32 transposed directly to d_out.
  auto gru_fn = [&](const unsigned short* xb, const unsigned short* yb_,
                    const unsigned short* w6, unsigned short* ob, float* of, bool last){
    { GP p{}; p.A=yb_; p.A2=xb; p.B=w6; p.B2=w6+M1; p.sBz=2*M1;
      p.O1=rxb; p.O2=zbb; p.XB=xb;
      p.K=2048; p.Ksplit=1024; p.lda=1024; p.ldb=1024; p.ldo=1024;
      gemm_k<128,64,11><<<dim3(16,32,2),256,0,stream>>>(p); }
    GP p{}; p.A=yb_; p.A2=rxb; p.B=w6+4*M1; p.B2=w6+5*M1;
    p.XB=xb; p.ZB=zbb; p.O1=ob; p.OF=of;
    p.K=2048; p.Ksplit=1024; p.lda=1024; p.ldb=1024; p.ldo=1024;
    if (last) gemm_k<128,64,14><<<dim3(16,32,1),256,0,stream>>>(p);
    else      gemm_k<128,64,12><<<dim3(16,32,1),256,0,stream>>>(p);
  };

  for (int l = 0; l < 4; ++l){
    // layer weights -> bf16 (single merged launch: 25600 blocks)
    conv5_k<<<25600,256,0,stream>>>(Wattn + (long)l*5242880,
                                    g1w   + (long)l*6291456,
                                    g2w   + (long)l*6291456,
                                    fw1   + (long)l*4194304,
                                    fw2   + (long)l*4194304, wb0);

    // nk = LN(concat(mem[l] f32, out bf16)); rows [4096:8192) are nq
    ln_k<<<8192,256,0,stream>>>(memin + (long)l*4194304, xbf, 4096,
                                ln1 + l*2048, ln1 + l*2048 + 1024, nkb);

    { // fused QKV + R: z=0 kh, z=1 vhT, z=2 qU/qV (*0.125), z=3 rh
      GP p{}; p.A=nkb; p.A2=posb; p.B=wb0;
      p.O1=khb; p.O2=vhTb; p.O3=qUb; p.O4=qVb; p.O5=rhb;
      p.bias1=Ub; p.bias2=Vb;
      p.K=1024; p.lda=1024; p.ldb=1024; p.ldo=1024;
      gemm_k<128,64,13><<<dim3(16,64,4),256,0,stream>>>(p); }

    attn_k<<<4096,256,0,stream>>>(qUb, qVb, khb, rhb, vhTb, ctxb);

    { // Y = gelu(ctx @ Wo^T)
      GP p{}; p.A=ctxb; p.B=wb0+4*M1; p.O1=yb;
      p.K=1024; p.lda=1024; p.ldb=1024; p.ldo=1024;
      gemm_k<128,64,6><<<dim3(16,32,1),256,0,stream>>>(p); }

    gru_fn(xbf, yb, wb0 + 5*M1, o1b, nullptr, false);

    ln_k<<<4096,256,0,stream>>>(nullptr, o1b, 0,
                                ln2 + l*2048, ln2 + l*2048 + 1024, Eb);

    { GP p{}; p.A=Eb;  p.B=wb0+17*M1; p.O1=F1b; p.bias1=fb1 + l*4096;
      p.K=1024; p.lda=1024; p.ldb=1024; p.ldo=4096;
      gemm_k<128,64,6><<<dim3(64,32,1),256,0,stream>>>(p); }
    { GP p{}; p.A=F1b; p.B=wb0+21*M1; p.O1=yb; p.bias1=fb2 + l*1024;
      p.K=4096; p.lda=4096; p.ldb=4096; p.ldo=1024;
      gemm_k<128,64,6><<<dim3(16,32,1),256,0,stream>>>(p); }

    gru_fn(o1b, yb, wb0 + 11*M1, xbf, (float*)d_out, l==3);
  }
}

// Round 13
// 2676.608 us; speedup vs baseline: 1.2172x; 1.0394x over previous
//
#include <hip/hip_runtime.h>
#include <hip/hip_bf16.h>

// Gated Transformer-XL forward.
// Dims: L=4, D=1024, NH=16, HD=64, CUR=512, MEM=512, BS=8, IN=512, FF=4096, FULL=1024
// Activation layout: (seq*BS, D), row = i*BS + b. All activations bf16.

typedef __attribute__((ext_vector_type(8))) __bf16 bfrag;
typedef __attribute__((ext_vector_type(4))) float f4;
typedef __attribute__((ext_vector_type(4))) unsigned short u16x4;
typedef __attribute__((ext_vector_type(8))) unsigned short u16x8;

__device__ __forceinline__ unsigned short f2bf(float f){
  union { float f; unsigned u; } v; v.f = f;
  unsigned r = v.u + 0x7fffu + ((v.u >> 16) & 1u);
  return (unsigned short)(r >> 16);
}
__device__ __forceinline__ float bf2f(unsigned short u){
  union { unsigned u; float f; } v; v.u = (unsigned)u << 16; return v.f;
}
__device__ __forceinline__ float geluf(float x){
  return 0.5f * x * (1.0f + erff(x * 0.7071067811865476f));
}
__device__ __forceinline__ float sigm(float x){ return 1.0f/(1.0f + __expf(-x)); }

__device__ __forceinline__ void gl_lds(const void* g, void* l){
  __builtin_amdgcn_global_load_lds(
    reinterpret_cast<const __attribute__((address_space(1))) unsigned int*>(
        reinterpret_cast<unsigned long>(g)),
    reinterpret_cast<__attribute__((address_space(3))) unsigned int*>(
        reinterpret_cast<unsigned long>(l)),
    16, 0, 0);
}

// ---------------------------------------------------------------------------
// Dense GEMM: C[M,N] = A[M,K] @ B[N,K]^T (bf16, row-major). Optional K-concat.
// BK=64 mega-steps (4 LDS buffers, one barrier per 64-K). XCD-aware swizzle.
// (Round-9 proven body: best-measured. Ring/counted-vmcnt variants are NULL
// at this 2-barrier structure per the T3/T4 regime gate — round-12 evidence.)
// EPI: 6  O1 = bf(gelu(acc + bias1))
//      11 z==0: O1 = bf(sigm(acc) * XB)  (GRU r-gate * x) | z==1: O2 = bf(sigm(acc-2))
//      12 o = (1-Z)*X + Z*tanh(acc); O1 = bf(o)            (GRU combine)
//      14 as 12 but OF[d_out] = o, f32, (b,i)-transposed   (final layer)
//      13 fused QKV+R: z=0 kh, z=1 vhT-scatter, z=2 qU/qV(+bias, *0.125), z=3 rh
// ---------------------------------------------------------------------------
struct GP {
  const unsigned short* A;
  const unsigned short* A2;
  const unsigned short* B;
  const unsigned short* B2;
  unsigned short* O1;
  unsigned short* O2;
  unsigned short* O3;
  unsigned short* O4;
  unsigned short* O5;
  float* OF;
  const float* bias1;
  const float* bias2;
  const unsigned short* XB;
  const unsigned short* ZB;
  int K, Ksplit, lda, ldb, ldo;
  int sBz;
};

template<int BM, int BN, int EPI>
__global__ __launch_bounds__(256) void gemm_k(GP p){
  __shared__ unsigned short As[2][2][BM*32];
  __shared__ unsigned short Bs[2][2][BN*32];
  const int tid  = threadIdx.x;
  const int lane = tid & 63;
  const int wid  = tid >> 6;
  const int lr   = lane & 15;
  const int lg   = lane >> 4;
  constexpr int FM = BM/32, FN = BN/32;

  // XCD swizzle (bijective; all grids have nwg%8==0)
  int bx = blockIdx.x, by = blockIdx.y;
  {
    const int gx = gridDim.x;
    const int nwg = gx * gridDim.y;
    if ((nwg & 7) == 0){
      const int bid = by*gx + bx;
      const int vid = (bid & 7)*(nwg >> 3) + (bid >> 3);
      bx = vid % gx;
      by = vid / gx;
    }
  }
  const int m0 = by * BM;
  const int n0 = bx * BN;
  const int z  = blockIdx.z;

  const unsigned short* Abase = p.A;
  const unsigned short* Bbase = p.B;
  if constexpr (EPI==13){
    if (z==2){ if (by >= 32) return; Abase = p.A + 4194304; }
    if (z==3){ if (by >= 8)  return; Abase = p.A2; }
    const int zsel = (z==0)?1:((z==1)?2:((z==2)?0:3));
    Bbase = p.B + (long)zsel*1048576;
  }

  const int ksp = p.Ksplit ? p.Ksplit : p.K;
  const unsigned short* AbL = Abase + (long)m0*p.lda;
  const unsigned short* AbH = p.A2 && EPI!=13 ? (p.A2 + (long)m0*p.lda - ksp) : AbL;
  const unsigned short* BbL = Bbase + (long)z*p.sBz + (long)n0*p.ldb;
  const unsigned short* BbH = p.B2 ? (p.B2 + (long)z*p.sBz + (long)n0*p.ldb - ksp) : BbL;

  const int srow = tid >> 2;          // 0..63
  const int skk  = (tid & 3) * 8;

  f4 acc[FM][FN];
  f4 zero4 = {0.0f, 0.0f, 0.0f, 0.0f};
  #pragma unroll
  for (int m=0;m<FM;m++)
    #pragma unroll
    for (int n=0;n<FN;n++) acc[m][n] = zero4;

  auto stage = [&](int buf, int sub, int k0){
    const unsigned short* A_ = (k0 < ksp) ? AbL : AbH;
    #pragma unroll
    for (int q=0;q<BM/64;q++)
      gl_lds(A_ + (long)(q*64 + srow)*p.lda + k0 + skk, (char*)As[buf][sub] + q*4096 + wid*1024);
    const unsigned short* B_ = (k0 < ksp) ? BbL : BbH;
    #pragma unroll
    for (int q=0;q<BN/64;q++)
      gl_lds(B_ + (long)(q*64 + srow)*p.ldb + k0 + skk, (char*)Bs[buf][sub] + q*4096 + wid*1024);
  };

  const int nk2 = p.K >> 6;
  stage(0,0,0); stage(0,1,32);
  __syncthreads();

  int cur = 0;
  for (int t = 0; t < nk2; ++t){
    if (t+1 < nk2){
      stage(cur^1, 0, (t+1)*64);
      stage(cur^1, 1, (t+1)*64 + 32);
    }
    #pragma unroll
    for (int sub=0; sub<2; ++sub){
      bfrag af[FM], bfr[FN];
      #pragma unroll
      for (int m=0;m<FM;m++)
        af[m] = *(const bfrag*)&As[cur][sub][((wid>>1)*(BM/2) + m*16 + lr)*32 + lg*8];
      #pragma unroll
      for (int n=0;n<FN;n++)
        bfr[n] = *(const bfrag*)&Bs[cur][sub][((wid&1)*(BN/2) + n*16 + lr)*32 + lg*8];
      #pragma unroll
      for (int m=0;m<FM;m++)
        #pragma unroll
        for (int n=0;n<FN;n++)
          acc[m][n] = __builtin_amdgcn_mfma_f32_16x16x32_bf16(af[m], bfr[n], acc[m][n], 0, 0, 0);
    }
    __syncthreads();   // drains vmcnt(0): mega-tile t+1 resident; buffers reusable
    cur ^= 1;
  }

  const int wr0 = m0 + (wid>>1)*(BM/2);
  const int wc0 = n0 + (wid&1)*(BN/2);
  #pragma unroll
  for (int m=0;m<FM;m++)
    #pragma unroll
    for (int n=0;n<FN;n++)
      #pragma unroll
      for (int r=0;r<4;r++){
        const int gr = wr0 + m*16 + lg*4 + r;
        const int gc = wc0 + n*16 + lr;
        const float a = acc[m][n][r];
        const long base = (long)gr*p.ldo + gc;
        if constexpr (EPI==6){
          const float t = a + (p.bias1 ? p.bias1[gc] : 0.0f);
          p.O1[base] = f2bf(geluf(t));
        }
        else if constexpr (EPI==11){
          const long ix = (long)gr*1024 + gc;
          if (z==0) p.O1[ix] = f2bf(sigm(a) * bf2f(p.XB[ix]));
          else      p.O2[ix] = f2bf(sigm(a - 2.0f));
        }
        else if constexpr (EPI==12){
          const long ix = (long)gr*1024 + gc;
          const float zz = bf2f(p.ZB[ix]);
          const float oo = (1.0f - zz)*bf2f(p.XB[ix]) + zz*tanhf(a);
          p.O1[ix] = f2bf(oo);
        }
        else if constexpr (EPI==14){
          const long ix = (long)gr*1024 + gc;
          const float zz = bf2f(p.ZB[ix]);
          const float oo = (1.0f - zz)*bf2f(p.XB[ix]) + zz*tanhf(a);
          const int i_ = gr >> 3, b_ = gr & 7;
          p.OF[(long)b_*524288 + (long)i_*1024 + gc] = oo;
        }
        else if constexpr (EPI==13){
          const long ix = (long)gr*1024 + gc;
          if (z==0){ p.O1[ix] = f2bf(a); }
          else if (z==1){
            const int b_ = gr & 7, js = gr >> 3, h_ = gc >> 6, d_ = gc & 63;
            p.O2[(long)(b_*16 + h_)*65536 + (long)d_*1024 + js] = f2bf(a);
          }
          else if (z==2){ p.O3[ix] = f2bf((a + p.bias1[gc])*0.125f);
                          p.O4[ix] = f2bf((a + p.bias2[gc])*0.125f); }
          else { p.O5[ix] = f2bf(a); }
        }
      }
}

// ---------------------------------------------------------------------------
// Fused relative attention (round-9 exact: 256,3; VGPR 84, no spill).
// Any launch_bounds >3 spills this body (rounds 4/6/10 evidence).
// ---------------------------------------------------------------------------
__global__ __launch_bounds__(256,3) void attn_k(const unsigned short* __restrict__ qU,
                                                const unsigned short* __restrict__ qV,
                                                const unsigned short* __restrict__ kh,
                                                const unsigned short* __restrict__ rh,
                                                const unsigned short* __restrict__ vhT,
                                                unsigned short* __restrict__ ctx){
  __shared__ char Sm[20480];          // band (528*38=20064) / P-chunks (4KB) / po @4096 (16KB)
  __shared__ float redm[4][16];
  __shared__ float reds[4][16];
  __shared__ float invd[16];
  const int tid = threadIdx.x;
  const int w   = tid >> 6;
  const int lane= tid & 63;
  const int lr  = lane & 15;
  const int lg  = lane >> 4;
  const int id = blockIdx.x;
  const int b  = id & 7;              // id%8 -> XCD: per-b kh/vhT slice stays in one L2
  const int i0 = ((id >> 3) & 31) * 16;
  const int h  = id >> 8;
  const int gmax = i0 >> 4;           // last valid 16-col group in half1
  const long hoff = (long)h * 64;
  const f4 z4 = {0.f,0.f,0.f,0.f};

  bfrag bqv[2];
  #pragma unroll
  for (int kk=0;kk<2;kk++)
    bqv[kk] = *(const bfrag*)(qV + ((long)(i0 + lr)*8 + b)*1024 + hoff + kk*32 + lg*8);
  bfrag aq[2];
  #pragma unroll
  for (int kk=0;kk<2;kk++)
    aq[kk] = *(const bfrag*)(qU + ((long)(i0 + lr)*8 + b)*1024 + hoff + kk*32 + lg*8);

  const int nv1 = (gmax >= w) ? (((gmax - w) >> 2) + 1) : 0;  // half1 valid prefix len

  f4 s[16];

#define LDK(DST, n_) { \
    const int cbx = c0 + (w + 4*(n_))*16; \
    DST[0] = *(const bfrag*)(kh + ((long)(cbx + lr)*8 + b)*1024 + hoff + lg*8); \
    DST[1] = *(const bfrag*)(kh + ((long)(cbx + lr)*8 + b)*1024 + hoff + 32 + lg*8); }

#define AC_CMP(n_, CUR) { \
    const int cbx = c0 + (w + 4*(n_))*16; \
    f4 a = z4; \
    __builtin_amdgcn_s_setprio(1); \
    a = __builtin_amdgcn_mfma_f32_16x16x32_bf16(aq[0], CUR[0], a, 0,0,0); \
    a = __builtin_amdgcn_mfma_f32_16x16x32_bf16(aq[1], CUR[1], a, 0,0,0); \
    __builtin_amdgcn_s_setprio(0); \
    _Pragma("unroll") \
    for (int q=0;q<4;q++){ \
      const int di = lg*4 + q; \
      const int jc = cbx + lr; \
      if (jc > i0 + di + 512) a[q] = -1e30f; \
      else { \
        const int rr = jc - di + radd; \
        a[q] += bf2f(*(const unsigned short*)(Sm + rr*38 + di*2)); \
      } \
    } \
    s[half*8 + n_] = a; }

#define AC_STEP(n_, CUR, NXT) \
    if ((n_)+2 < nv) LDK(NXT, (n_)+2); \
    if ((n_) < nv) AC_CMP(n_, CUR) \
    else s[half*8 + n_] = (f4){-1e30f,-1e30f,-1e30f,-1e30f};

  #pragma unroll
  for (int half=0; half<2; ++half){
    const int c0    = half*512;
    const int rbase = half ? (1008 - i0) : (496 - i0);
    const int ntil  = half ? (gmax + 1) : 33;
    const int radd  = half ? -497 : 15;      // rr = jc - di + radd
    // ---- band fill: BDpre^T rows rr, cols di ----
    for (int mt = w; mt < ntil; mt += 4){
      const int r0 = rbase + mt*16;
      f4 acc = z4;
      #pragma unroll
      for (int kk=0;kk<2;kk++){
        bfrag ar = *(const bfrag*)(rh + (long)(r0 + lr)*1024 + hoff + kk*32 + lg*8);
        acc = __builtin_amdgcn_mfma_f32_16x16x32_bf16(ar, bqv[kk], acc, 0,0,0);
      }
      #pragma unroll
      for (int q=0;q<4;q++){
        const int rr = mt*16 + lg*4 + q;
        *(unsigned short*)(Sm + rr*38 + lr*2) = f2bf(acc[q]);
      }
    }
    __syncthreads();
    // ---- AC + BD, 2-deep kh prefetch, valid groups form a prefix ----
    const int nv = (half==0) ? 8 : nv1;
    {
      bfrag bkA[2], bkB[2], bkC[2];
      if (0 < nv) LDK(bkA, 0);
      if (1 < nv) LDK(bkB, 1);
      AC_STEP(0, bkA, bkC)
      AC_STEP(1, bkB, bkA)
      AC_STEP(2, bkC, bkB)
      AC_STEP(3, bkA, bkC)
      AC_STEP(4, bkB, bkA)
      AC_STEP(5, bkC, bkB)
      AC_STEP(6, bkA, bkC)
      AC_STEP(7, bkB, bkA)
    }
    __syncthreads();   // all band reads done before next half / P staging
  }

  // ---- pre-issue vhT chunk 0 (hides under softmax) ----
  const unsigned short* vb_base = vhT + (long)(b*16 + h)*65536;

#define LDV(DST, t_) { \
    const int c0v = ((t_) >> 2) * 512; \
    const int tau = (t_) & 3; \
    const int jA = c0v + (w + 8*tau)*16; \
    const int jB = c0v + (w + 8*tau + 4)*16; \
    const int jcol = (lg < 2) ? (jA + lg*8) : (jB + (lg-2)*8); \
    _Pragma("unroll") \
    for (int nd=0; nd<4; nd++) \
      DST[nd] = *(const bfrag*)(vb_base + (long)(nd*16 + lr)*1024 + jcol); }

#define CHV(t_) ((t_) < 4 || (2*((t_)-4) < nv1))

  bfrag vbA[4], vbB[4];
  LDV(vbA, 0);

  // ---- softmax stats over full 1024 cols ----
  float mx[4], sum[4];
  #pragma unroll
  for (int q=0;q<4;q++){
    float m = s[0][q];
    #pragma unroll
    for (int n=1;n<16;n++) m = fmaxf(m, s[n][q]);
    m = fmaxf(m, __shfl_xor(m, 1));
    m = fmaxf(m, __shfl_xor(m, 2));
    m = fmaxf(m, __shfl_xor(m, 4));
    m = fmaxf(m, __shfl_xor(m, 8));
    if (lr == 0) redm[w][lg*4+q] = m;
  }
  __syncthreads();
  #pragma unroll
  for (int q=0;q<4;q++){
    const int row = lg*4+q;
    mx[q] = fmaxf(fmaxf(redm[0][row], redm[1][row]), fmaxf(redm[2][row], redm[3][row]));
    sum[q] = 0.0f;
  }
  #pragma unroll
  for (int n=0;n<16;n++)
    #pragma unroll
    for (int q=0;q<4;q++){
      const float e = __expf(s[n][q] - mx[q]);
      s[n][q] = e;
      sum[q] += e;
    }
  #pragma unroll
  for (int q=0;q<4;q++){
    float v = sum[q];
    v += __shfl_xor(v, 1);
    v += __shfl_xor(v, 2);
    v += __shfl_xor(v, 4);
    v += __shfl_xor(v, 8);
    if (lr == 0) reds[w][lg*4+q] = v;
  }
  __syncthreads();
  if (tid < 16)
    invd[tid] = 1.0f / (reds[0][tid] + reds[1][tid] + reds[2][tid] + reds[3][tid]);

  // ---- PV: per-wave over its valid 32-col chunks, 1-deep vhT prefetch ----
  f4 oac[4];
  #pragma unroll
  for (int nd=0;nd<4;nd++) oac[nd] = z4;
  char* Pch = Sm + w*1024;            // [16 rows][32 cols] u16, swizzled

#define PV_STEP(t_, CUR, NXT) \
    if ((t_)+1 < 8 && CHV((t_)+1)) LDV(NXT, (t_)+1); \
    if (CHV(t_)){ \
      const int s0i = (((t_)<4)?0:8) + ((t_)&3)*2; \
      _Pragma("unroll") \
      for (int nn=0;nn<2;nn++){ \
        const f4 e = s[s0i + nn]; \
        _Pragma("unroll") \
        for (int q=0;q<4;q++){ \
          const int row = lg*4 + q; \
          const int col = nn*16 + lr; \
          *(unsigned short*)(Pch + row*64 + ((col*2) ^ (((row>>2)&3)<<4))) = f2bf(e[q]); \
        } \
      } \
      bfrag pa = *(const bfrag*)(Pch + lr*64 + ((lg*16) ^ (((lr>>2)&3)<<4))); \
      __builtin_amdgcn_s_setprio(1); \
      _Pragma("unroll") \
      for (int nd=0;nd<4;nd++) \
        oac[nd] = __builtin_amdgcn_mfma_f32_16x16x32_bf16(pa, CUR[nd], oac[nd], 0,0,0); \
      __builtin_amdgcn_s_setprio(0); \
    }

  PV_STEP(0, vbA, vbB)
  PV_STEP(1, vbB, vbA)
  PV_STEP(2, vbA, vbB)
  PV_STEP(3, vbB, vbA)
  PV_STEP(4, vbA, vbB)
  PV_STEP(5, vbB, vbA)
  PV_STEP(6, vbA, vbB)
  PV_STEP(7, vbB, vbA)

  // partial O to LDS
  float* po = (float*)(Sm + 4096 + w*4096);   // [16][64] f32
  #pragma unroll
  for (int nd=0;nd<4;nd++)
    #pragma unroll
    for (int q=0;q<4;q++)
      po[(lg*4+q)*64 + nd*16 + lr] = oac[nd][q];
  __syncthreads();
  // ---- merge + normalize + write ----
  {
    const int row = tid >> 4;
    const int d0  = (tid & 15) * 4;
    f4 v = *(const f4*)(Sm + 4096 + (row*64 + d0)*4);
    #pragma unroll
    for (int ww=1;ww<4;ww++){
      const f4 u = *(const f4*)(Sm + 4096 + ww*4096 + (row*64 + d0)*4);
      v.x += u.x; v.y += u.y; v.z += u.z; v.w += u.w;
    }
    const float iv = invd[row];
    u16x4 o;
    o.x = f2bf(v.x*iv); o.y = f2bf(v.y*iv); o.z = f2bf(v.z*iv); o.w = f2bf(v.w*iv);
    *(u16x4*)(ctx + ((long)(i0 + row)*8 + b)*1024 + hoff + d0) = o;
  }
#undef LDK
#undef AC_CMP
#undef AC_STEP
#undef LDV
#undef CHV
#undef PV_STEP
}

// ---------------------------------------------------------------------------
// LayerNorm: rows < splitRow read f32 srcA; rows >= splitRow read bf16 srcB.
__global__ __launch_bounds__(256) void ln_k(const float* __restrict__ srcA,
                                            const unsigned short* __restrict__ srcB, int splitRow,
                                            const float* __restrict__ g, const float* __restrict__ b,
                                            unsigned short* __restrict__ dst){
  const int row = blockIdx.x;
  const int t = threadIdx.x;
  float4 v;
  if (row < splitRow){
    v = ((const float4*)(srcA + (long)row*1024))[t];
  } else {
    u16x4 uv = *(const u16x4*)(srcB + (long)(row - splitRow)*1024 + t*4);
    v.x = bf2f(uv.x); v.y = bf2f(uv.y); v.z = bf2f(uv.z); v.w = bf2f(uv.w);
  }
  float s1 = v.x+v.y+v.z+v.w;
  float s2 = v.x*v.x+v.y*v.y+v.z*v.z+v.w*v.w;
  #pragma unroll
  for (int o=32;o;o>>=1){ s1 += __shfl_xor(s1,o); s2 += __shfl_xor(s2,o); }
  __shared__ float r1[4], r2[4];
  const int w = t>>6;
  if ((t&63)==0){ r1[w]=s1; r2[w]=s2; }
  __syncthreads();
  s1 = r1[0]+r1[1]+r1[2]+r1[3];
  s2 = r2[0]+r2[1]+r2[2]+r2[3];
  const float mean = s1*(1.0f/1024.0f);
  const float var  = s2*(1.0f/1024.0f) - mean*mean;
  const float rs   = rsqrtf(var + 1e-5f);
  float4 gg = ((const float4*)g)[t];
  float4 bb = ((const float4*)b)[t];
  u16x4 o;
  o.x = f2bf((v.x-mean)*rs*gg.x + bb.x);
  o.y = f2bf((v.y-mean)*rs*gg.y + bb.y);
  o.z = f2bf((v.z-mean)*rs*gg.z + bb.z);
  o.w = f2bf((v.w-mean)*rs*gg.w + bb.w);
  *(u16x4*)(dst + (long)row*1024 + t*4) = o;
}

__global__ __launch_bounds__(256) void conv_k(const float* __restrict__ s,
                                              unsigned short* __restrict__ d, long n){
  long i = ((long)blockIdx.x*256 + threadIdx.x)*4;
  if (i >= n) return;
  float4 v = *(const float4*)(s + i);
  u16x4 o; o.x=f2bf(v.x); o.y=f2bf(v.y); o.z=f2bf(v.z); o.w=f2bf(v.w);
  *(u16x4*)(d + i) = o;
}

// one launch converts all 5 weight blocks of a layer into contiguous wb0
__global__ __launch_bounds__(256) void conv5_k(const float* __restrict__ wat,
                                               const float* __restrict__ g1,
                                               const float* __restrict__ g2,
                                               const float* __restrict__ f1,
                                               const float* __restrict__ f2,
                                               unsigned short* __restrict__ dst){
  const long i = ((long)blockIdx.x*256 + threadIdx.x)*4;   // < 26214400
  const float* s; long off;
  if      (i <  5242880){ s = wat; off = 0; }
  else if (i < 11534336){ s = g1;  off = 5242880; }
  else if (i < 17825792){ s = g2;  off = 11534336; }
  else if (i < 22020096){ s = f1;  off = 17825792; }
  else                  { s = f2;  off = 22020096; }
  float4 v = *(const float4*)(s + (i - off));
  u16x4 o; o.x=f2bf(v.x); o.y=f2bf(v.y); o.z=f2bf(v.z); o.w=f2bf(v.w);
  *(u16x4*)(dst + i) = o;
}

__global__ __launch_bounds__(128) void ht_k(const float* __restrict__ h,
                                            unsigned short* __restrict__ d){
  const int row = blockIdx.x;           // i*8+b
  const int i = row>>3, b = row&7;
  const float* src = h + ((long)b*512 + i)*512;
  const int t = threadIdx.x;
  float4 v = ((const float4*)src)[t];
  u16x4 o; o.x=f2bf(v.x); o.y=f2bf(v.y); o.z=f2bf(v.z); o.w=f2bf(v.w);
  *(u16x4*)(d + (long)row*512 + t*4) = o;
}

__global__ __launch_bounds__(256) void pos_k(unsigned short* __restrict__ d){
  const int r = blockIdx.x, t = threadIdx.x;
  const float seq = (float)(1023 - r);
  u16x4 o;
  #pragma unroll
  for (int q=0;q<4;q++){
    const int c = t*4 + q;
    const int f = (c < 512) ? c : (c - 512);
    const float inv = expf((float)f * -0.017988946039016f); // -2*ln(1e4)/1024
    const float ang = seq * inv;
    const float val = (c < 512) ? sinf(ang) : cosf(ang);
    o[q] = f2bf(val);
  }
  *(u16x4*)(d + (long)r*1024 + t*4) = o;
}

// ---------------------------------------------------------------------------
extern "C" void kernel_launch(void* const* d_in, const int* in_sizes, int n_in,
                              void* d_out, int out_size, void* d_ws, size_t ws_size,
                              hipStream_t stream){
  (void)in_sizes; (void)n_in; (void)out_size; (void)ws_size;
  const float* h     = (const float*)d_in[0];
  const float* memin = (const float*)d_in[1];
  const float* Wemb  = (const float*)d_in[2];
  const float* bemb  = (const float*)d_in[3];
  const float* Ub    = (const float*)d_in[4];
  const float* Vb    = (const float*)d_in[5];
  const float* ln1   = (const float*)d_in[6];
  const float* ln2   = (const float*)d_in[7];
  const float* Wattn = (const float*)d_in[8];
  const float* g1w   = (const float*)d_in[9];
  const float* g2w   = (const float*)d_in[10];
  const float* fw1   = (const float*)d_in[11];
  const float* fb1   = (const float*)d_in[12];
  const float* fw2   = (const float*)d_in[13];
  const float* fb2   = (const float*)d_in[14];

  char* Wp = (char*)d_ws;
  size_t off = 0;
  auto take = [&](size_t bytes)->size_t{ size_t r = off; off += (bytes + 255) & ~(size_t)255; return r; };
  unsigned short* xbf  = (unsigned short*)(Wp + take( 8388608)); // out bf16
  unsigned short* o1b  = (unsigned short*)(Wp + take( 8388608)); // gru1 out bf16
  unsigned short* zbb  = (unsigned short*)(Wp + take( 8388608)); // gru z-gate bf16
  unsigned short* rxb  = (unsigned short*)(Wp + take( 8388608)); // r*x bf16
  unsigned short* yb   = (unsigned short*)(Wp + take( 8388608)); // Y / E2 bf16
  unsigned short* Eb   = (unsigned short*)(Wp + take( 8388608)); // LN2 out bf16
  unsigned short* wb0  = (unsigned short*)(Wp + take(52428800)); // layer weights bf16
  unsigned short* hTb  = (unsigned short*)(Wp + take( 4194304));
  unsigned short* webb = (unsigned short*)(Wp + take( 1048576));
  unsigned short* posb = (unsigned short*)(Wp + take( 2097152));
  unsigned short* nkb  = (unsigned short*)(Wp + take(16777216)); // LN'd key (full*bs, D)
  unsigned short* qUb  = (unsigned short*)(Wp + take( 8388608));
  unsigned short* qVb  = (unsigned short*)(Wp + take( 8388608));
  unsigned short* khb  = (unsigned short*)(Wp + take(16777216));
  unsigned short* vhTb = (unsigned short*)(Wp + take(16777216));
  unsigned short* F1b  = khb; // FF hidden (32MB) overlaps khb+vhTb (phase-disjoint)
  unsigned short* rhb  = (unsigned short*)(Wp + take( 2097152));
  unsigned short* ctxb = (unsigned short*)(Wp + take( 8388608));

  const int M1 = 1048576; // D*D elements

  // one-time prep
  conv_k<<<512, 256, 0, stream>>>(Wemb, webb, 524288);
  ht_k<<<4096, 128, 0, stream>>>(h, hTb);
  pos_k<<<1024, 256, 0, stream>>>(posb);

  { // embed: out = gelu(h @ Wemb^T + bemb)  (bf16)
    GP p{}; p.A=hTb; p.B=webb; p.O1=xbf; p.bias1=bemb;
    p.K=512; p.lda=512; p.ldb=512; p.ldo=1024;
    gemm_k<128,64,6><<<dim3(16,32,1),256,0,stream>>>(p);
  }

  // GRU (2 launches, K=2048 concat): x=xb, y=yb_, weights w6 = [Wr,Ur,Wz,Uz,Wg,Ug]
  // last=true: final-layer combine writes f32 transposed directly to d_out.
  auto gru_fn = [&](const unsigned short* xb, const unsigned short* yb_,
                    const unsigned short* w6, unsigned short* ob, float* of, bool last){
    { GP p{}; p.A=yb_; p.A2=xb; p.B=w6; p.B2=w6+M1; p.sBz=2*M1;
      p.O1=rxb; p.O2=zbb; p.XB=xb;
      p.K=2048; p.Ksplit=1024; p.lda=1024; p.ldb=1024; p.ldo=1024;
      gemm_k<128,64,11><<<dim3(16,32,2),256,0,stream>>>(p); }
    GP p{}; p.A=yb_; p.A2=rxb; p.B=w6+4*M1; p.B2=w6+5*M1;
    p.XB=xb; p.ZB=zbb; p.O1=ob; p.OF=of;
    p.K=2048; p.Ksplit=1024; p.lda=1024; p.ldb=1024; p.ldo=1024;
    if (last) gemm_k<128,64,14><<<dim3(16,32,1),256,0,stream>>>(p);
    else      gemm_k<128,64,12><<<dim3(16,32,1),256,0,stream>>>(p);
  };

  for (int l = 0; l < 4; ++l){
    // layer weights -> bf16 (single merged launch: 25600 blocks)
    conv5_k<<<25600,256,0,stream>>>(Wattn + (long)l*5242880,
                                    g1w   + (long)l*6291456,
                                    g2w   + (long)l*6291456,
                                    fw1   + (long)l*4194304,
                                    fw2   + (long)l*4194304, wb0);

    // nk = LN(concat(mem[l] f32, out bf16)); rows [4096:8192) are nq
    ln_k<<<8192,256,0,stream>>>(memin + (long)l*4194304, xbf, 4096,
                                ln1 + l*2048, ln1 + l*2048 + 1024, nkb);

    { // fused QKV + R: z=0 kh, z=1 vhT, z=2 qU/qV (*0.125), z=3 rh
      GP p{}; p.A=nkb; p.A2=posb; p.B=wb0;
      p.O1=khb; p.O2=vhTb; p.O3=qUb; p.O4=qVb; p.O5=rhb;
      p.bias1=Ub; p.bias2=Vb;
      p.K=1024; p.lda=1024; p.ldb=1024; p.ldo=1024;
      gemm_k<128,64,13><<<dim3(16,64,4),256,0,stream>>>(p); }

    attn_k<<<4096,256,0,stream>>>(qUb, qVb, khb, rhb, vhTb, ctxb);

    { // Y = gelu(ctx @ Wo^T)
      GP p{}; p.A=ctxb; p.B=wb0+4*M1; p.O1=yb;
      p.K=1024; p.lda=1024; p.ldb=1024; p.ldo=1024;
      gemm_k<128,64,6><<<dim3(16,32,1),256,0,stream>>>(p); }

    gru_fn(xbf, yb, wb0 + 5*M1, o1b, nullptr, false);

    ln_k<<<4096,256,0,stream>>>(nullptr, o1b, 0,
                                ln2 + l*2048, ln2 + l*2048 + 1024, Eb);

    { GP p{}; p.A=Eb;  p.B=wb0+17*M1; p.O1=F1b; p.bias1=fb1 + l*4096;
      p.K=1024; p.lda=1024; p.ldb=1024; p.ldo=4096;
      gemm_k<128,64,6><<<dim3(64,32,1),256,0,stream>>>(p); }
    { GP p{}; p.A=F1b; p.B=wb0+21*M1; p.O1=yb; p.bias1=fb2 + l*1024;
      p.K=4096; p.lda=4096; p.ldb=4096; p.ldo=1024;
      gemm_k<128,64,6><<<dim3(16,32,1),256,0,stream>>>(p); }

    gru_fn(o1b, yb, wb0 + 11*M1, xbf, (float*)d_out, l==3);
  }
}